// Round 15
// baseline (48.451 us; speedup 1.0000x reference)
//
#include <hip/hip_runtime.h>
#include <stdint.h>

#define B 64
#define G 32
#define A 25600
#define NC 2
#define NL 5
#define IOU_T 0.5f
#define VAR_C 0.1f
#define VAR_S 0.2f

#define MSPLIT 10
#define MCH (A / MSPLIT)    // 2560 anchors per fused block, 10 per thread
#define NH 10
#define PF 8                // fields per psplit record

#define NB2 256             // coarse value-histogram bins
#define BSCALE2 20.0f       // bin = int(closs * 20), clamped to 255
#define CANDCAP 8192        // per-batch candidate buffer capacity
#define ST 512              // select_kernel threads
#define NW (ST / 64)        // select waves

__device__ __forceinline__ float sl1(float x) {
    float ax = fabsf(x);
    return ax < 1.0f ? 0.5f * ax * ax : ax - 0.5f;
}

__device__ __forceinline__ int vbin(float closs) {
    int bin = (int)(closs * BSCALE2);
    return bin < 0 ? 0 : (bin > NB2 - 1 ? NB2 - 1 : bin);
}

// ---------------------------------------------------------------------------
// K1 FUSED match+loss: grid (B, MSPLIT) x 256, NH=10 anchors per thread.
//  - wave-bbox early-out for the IoU loop (exact; first-max argmax fixup)
//  - anchor float4 reloaded (L2-hot) in loss phase to cap VGPRs; corner
//    values stay in registers so threshold comparisons are bit-exact
//  - epilogue: wave shfl reduces + 1 LDS hop; per-wave neg hists
//  - per-(block,gt) best keys -> gsplit overwrite; resets gdone
// ---------------------------------------------------------------------------
__global__ __launch_bounds__(256) void fused_kernel(
    const float* __restrict__ cls_logits, const float* __restrict__ box_preds,
    const float* __restrict__ lmk_preds, const float* __restrict__ gaze_preds,
    const float* __restrict__ anchors, const float* __restrict__ gt_boxes,
    const int* __restrict__ gt_labels, const float* __restrict__ gt_lmk,
    const float* __restrict__ gt_gaze, signed char* __restrict__ matches,
    unsigned long long* __restrict__ gsplit, unsigned* __restrict__ negkey,
    unsigned* __restrict__ bhist, float* __restrict__ psplit,
    unsigned* __restrict__ gdone)
{
    const int b = blockIdx.x, s = blockIdx.y, tid = threadIdx.x;
    const int lane = tid & 63, wave = tid >> 6;
    __shared__ float4 sbox[G];
    __shared__ int sgorig[G], sinv[G];
    __shared__ unsigned long long sbest[G];
    __shared__ int s_nv;
    __shared__ float sgb[G * 4], slmk[G * NL * 2], sgz[G * 2];
    __shared__ int slab[G];
    __shared__ unsigned lhist[4][NB2];
    __shared__ float wred[4][8];

    if (b == 0 && s == 0 && tid == 0) *gdone = 0u;   // reset for select

    if (tid < G) {
        sbest[tid] = 0ULL;
        int valid = gt_labels[b * G + tid] > 0;
        unsigned long long mask = __ballot(valid);
        int pfx = __popcll(mask & ((1ULL << tid) - 1ULL));
        sinv[tid] = valid ? pfx : -1;
        if (valid) {
            sbox[pfx] = *(const float4*)(gt_boxes + (b * G + tid) * 4);
            sgorig[pfx] = tid;
        }
        if (tid == 0) s_nv = (int)__popcll(mask);
    }
    for (int i = tid; i < G * 4; i += 256) sgb[i] = gt_boxes[b * G * 4 + i];
    for (int i = tid; i < G * NL * 2; i += 256) slmk[i] = gt_lmk[b * G * NL * 2 + i];
    for (int i = tid; i < G * 2; i += 256) sgz[i] = gt_gaze[b * G * 2 + i];
    if (tid < G) slab[tid] = gt_labels[b * G + tid];
    for (int i = tid; i < 4 * NB2; i += 256) ((unsigned*)lhist)[i] = 0u;
    __syncthreads();
    const int nv = s_nv;

    signed char* mrow = matches + (size_t)b * A;
    const int a0 = s * MCH;

    // ---- match phase: NH anchors per thread ----
    float ax0[NH], ay0[NH], ax1[NH], ay1[NH], aa[NH];
    #pragma unroll
    for (int h = 0; h < NH; ++h) {
        const int a = a0 + tid + 256 * h;
        float4 an = *(const float4*)(anchors + a * 4);
        ax0[h] = an.x - an.z * 0.5f;
        ay0[h] = an.y - an.w * 0.5f;
        ax1[h] = an.x + an.z * 0.5f;
        ay1[h] = an.y + an.w * 0.5f;
        aa[h] = (ax1[h] - ax0[h]) * (ay1[h] - ay0[h]);  // reference float path
    }

    // wave bbox of the NH*64 anchors this wave owns
    float wx0 = ax0[0], wy0 = ay0[0], wx1 = ax1[0], wy1 = ay1[0];
    #pragma unroll
    for (int h = 1; h < NH; ++h) {
        wx0 = fminf(wx0, ax0[h]); wy0 = fminf(wy0, ay0[h]);
        wx1 = fmaxf(wx1, ax1[h]); wy1 = fmaxf(wy1, ay1[h]);
    }
    #pragma unroll
    for (int off = 32; off > 0; off >>= 1) {
        wx0 = fminf(wx0, __shfl_down(wx0, off));
        wy0 = fminf(wy0, __shfl_down(wy0, off));
        wx1 = fmaxf(wx1, __shfl_down(wx1, off));
        wy1 = fmaxf(wy1, __shfl_down(wy1, off));
    }
    wx0 = __shfl(wx0, 0); wy0 = __shfl(wy0, 0);
    wx1 = __shfl(wx1, 0); wy1 = __shfl(wy1, 0);

    float best[NH];
    int bci[NH];
    #pragma unroll
    for (int h = 0; h < NH; ++h) { best[h] = -2.0f; bci[h] = 0; }

    for (int ci = 0; ci < nv; ++ci) {
        float4 bb = sbox[ci];                       // broadcast ds_read_b128
        if (bb.x < wx1 && bb.z > wx0 && bb.y < wy1 && bb.w > wy0) {
            float area = (bb.z - bb.x) * (bb.w - bb.y); // reference formula
            float inter[NH], iou[NH];
            bool anyh = false;
            #pragma unroll
            for (int h = 0; h < NH; ++h) {
                float iw = fmaxf(fminf(bb.z, ax1[h]) - fmaxf(bb.x, ax0[h]), 0.0f);
                float ih = fmaxf(fminf(bb.w, ay1[h]) - fmaxf(bb.y, ay0[h]), 0.0f);
                inter[h] = iw * ih;
                iou[h] = 0.0f;                      // exact: 0/den == +0.0
                anyh = anyh || (inter[h] > 0.0f);
            }
            if (__any(anyh)) {                      // wave-uniform skip
                unsigned long long km = 0ULL;
                #pragma unroll
                for (int h = 0; h < NH; ++h) {
                    iou[h] = inter[h] / (area + aa[h] - inter[h] + 1e-9f);
                    const int a = a0 + tid + 256 * h;
                    unsigned long long key =
                        ((unsigned long long)__float_as_uint(iou[h]) << 32) |
                        (unsigned)(0xFFFFFFFFu - (unsigned)a);
                    if (key > km) km = key;
                }
                #pragma unroll
                for (int off = 32; off > 0; off >>= 1) {
                    unsigned long long o = __shfl_down(km, off);
                    if (o > km) km = o;
                }
                if (lane == 0 && km > sbest[ci]) atomicMax(&sbest[ci], km);
            }
            #pragma unroll
            for (int h = 0; h < NH; ++h)
                if (iou[h] > best[h]) { best[h] = iou[h]; bci[h] = ci; }  // first-max
        } else {
            // all lanes: iou == +0 exactly; first-max argmax fixup
            #pragma unroll
            for (int h = 0; h < NH; ++h)
                if (best[h] < 0.0f) { best[h] = 0.0f; bci[h] = ci; }
        }
    }

    // ---- loss phase (match result from registers; anchor reloaded L2-hot) --
    const float* lrow = cls_logits + (size_t)b * A * NC;
    unsigned* krow = negkey + (size_t)b * A;

    float pos_sum = 0, box_sum = 0, lmk_sum = 0, gaze_sum = 0;
    float pos_cnt = 0, face_cnt = 0;

    #pragma unroll
    for (int h = 0; h < NH; ++h) {
        const int a = a0 + tid + 256 * h;
        const int v = (best[h] >= IOU_T) ? sgorig[bci[h]] : -1;
        mrow[a] = (signed char)v;
        float2 xl = *(const float2*)(lrow + a * 2);
        float x0 = xl.x, x1 = xl.y;
        float mx = fmaxf(x0, x1);
        float lse = mx + logf(expf(x0 - mx) + expf(x1 - mx));
        unsigned key = 0;
        if (v < 0) {
            float closs = lse - x0;   // label 0; closs > 0
            unsigned bits = __float_as_uint(closs);
            key = bits ^ ((bits & 0x80000000u) ? 0xFFFFFFFFu : 0x80000000u);
            atomicAdd(&lhist[wave][vbin(closs)], 1u);
        } else {
            int m = v;
            int lab = slab[m];
            float xc = (lab >= 1) ? x1 : x0;   // NC==2
            pos_sum += lse - xc;
            pos_cnt += 1.0f;
            float4 an = *(const float4*)(anchors + a * 4);   // L2-hot reload
            float dcx = an.x, dcy = an.y, dw = an.z, dh = an.w;
            float bx0 = sgb[m * 4], by0 = sgb[m * 4 + 1];
            float bx1 = sgb[m * 4 + 2], by1 = sgb[m * 4 + 3];
            float gcx = (bx0 + bx1) * 0.5f, gcy = (by0 + by1) * 0.5f;
            float gw = bx1 - bx0, gh = by1 - by0;
            float off0 = ((gcx - dcx) / dw) / VAR_C;
            float off1 = ((gcy - dcy) / dh) / VAR_C;
            float off2 = logf(fmaxf(gw / dw, 1e-6f)) / VAR_S;
            float off3 = logf(fmaxf(gh / dh, 1e-6f)) / VAR_S;
            float4 bp = *(const float4*)(box_preds + ((size_t)b * A + a) * 4);
            box_sum += sl1(bp.x - off0) + sl1(bp.y - off1) +
                       sl1(bp.z - off2) + sl1(bp.w - off3);
            if (lab == 1) {  // FACE
                face_cnt += 1.0f;
                const float* lp = lmk_preds + ((size_t)b * A + a) * (NL * 2);
                #pragma unroll
                for (int i = 0; i < NL; ++i) {
                    float tx = ((slmk[m * NL * 2 + 2 * i] - dcx) / dw) / VAR_C;
                    float ty = ((slmk[m * NL * 2 + 2 * i + 1] - dcy) / dh) / VAR_C;
                    lmk_sum += sl1(lp[2 * i] - tx) + sl1(lp[2 * i + 1] - ty);
                }
                const float* gp = gaze_preds + ((size_t)b * A + a) * 2;
                gaze_sum += sl1(gp[0] - sgz[m * 2]) + sl1(gp[1] - sgz[m * 2 + 1]);
            }
        }
        krow[a] = key;
    }

    // ---- epilogue: wave shfl reduce + 1 LDS hop (2 barriers total) ----
    #pragma unroll
    for (int off = 32; off > 0; off >>= 1) {
        pos_sum += __shfl_down(pos_sum, off);
        box_sum += __shfl_down(box_sum, off);
        lmk_sum += __shfl_down(lmk_sum, off);
        gaze_sum += __shfl_down(gaze_sum, off);
        pos_cnt += __shfl_down(pos_cnt, off);
        face_cnt += __shfl_down(face_cnt, off);
    }
    if (lane == 0) {
        wred[wave][0] = pos_sum; wred[wave][1] = box_sum;
        wred[wave][2] = lmk_sum; wred[wave][3] = gaze_sum;
        wred[wave][4] = pos_cnt; wred[wave][5] = face_cnt;
    }
    __syncthreads();   // wred + lhist + sbest all complete
    if (tid < 6) {
        psplit[(b * MSPLIT + s) * PF + tid] =
            wred[0][tid] + wred[1][tid] + wred[2][tid] + wred[3][tid];
    }
    bhist[(b * MSPLIT + s) * NB2 + tid] =
        lhist[0][tid] + lhist[1][tid] + lhist[2][tid] + lhist[3][tid];
    if (tid < G) {
        int ci = sinv[tid];
        gsplit[((size_t)b * MSPLIT + s) * G + tid] = (ci >= 0) ? sbest[ci] : 0ULL;
    }
}

// ---------------------------------------------------------------------------
// K2 select: grid B x 512.  Wave-0 shfl suffix scans, per-wave radix hists,
// ballot-aggregated compaction, forced-match fixup, last-block finalize.
// ---------------------------------------------------------------------------
__global__ __launch_bounds__(ST) void select_kernel(
    const float* __restrict__ cls_logits, const float* __restrict__ box_preds,
    const float* __restrict__ lmk_preds, const float* __restrict__ gaze_preds,
    const float* __restrict__ anchors, const float* __restrict__ gt_boxes,
    const int* __restrict__ gt_labels, const float* __restrict__ gt_lmk,
    const float* __restrict__ gt_gaze, const signed char* __restrict__ matches,
    const unsigned long long* __restrict__ gsplit,
    unsigned* __restrict__ negkey, const unsigned* __restrict__ bhist,
    const float* __restrict__ psplit, unsigned* __restrict__ candbuf,
    float* __restrict__ partials, unsigned* __restrict__ gdone,
    float* __restrict__ out)
{
    const int b = blockIdx.x, tid = threadIdx.x;
    const int lane = tid & 63, wv = tid >> 6;
    __shared__ unsigned lhist[NB2];
    __shared__ unsigned whist[NW][256];
    __shared__ float accs[8];
    __shared__ float swred[NW];
    __shared__ int s_t, s_fin;
    __shared__ unsigned s_kk, s_candN, s_pfx, s_k2;

    unsigned* krow = negkey + (size_t)b * A;
    const uint4* krow4 = (const uint4*)krow;
    const float* lrow = cls_logits + (size_t)b * A * NC;
    unsigned* cand = candbuf + (size_t)b * CANDCAP;

    // ---- phase 0: merge psplit + bhist ----
    if (tid < 6) {
        float v = 0;
        for (int s2 = 0; s2 < MSPLIT; ++s2) v += psplit[(b * MSPLIT + s2) * PF + tid];
        accs[tid] = v;
    }
    if (tid < NB2) {
        unsigned v = 0;
        const unsigned* hb = bhist + (size_t)b * MSPLIT * NB2 + tid;
        for (int s2 = 0; s2 < MSPLIT; ++s2) v += hb[s2 * NB2];
        lhist[tid] = v;
    }
    if (tid == 0) s_candN = 0;
    __syncthreads();

    // ---- phase 1: fixup (forced matches) ----
    float f0 = 0, f1 = 0, f2 = 0, f3 = 0, f4 = 0, f5 = 0;
    int fbin = -1, fa = -1;
    if (tid < 32) {
        const int g = tid;
        int lab = gt_labels[b * G + g];
        unsigned long long kb = 0ULL;
        const unsigned long long* gs = gsplit + (size_t)b * MSPLIT * G + g;
        for (int s2 = 0; s2 < MSPLIT; ++s2) {
            unsigned long long v = gs[(size_t)s2 * G];
            if (v > kb) kb = v;
        }
        int a_c = -1;
        if (lab > 0 && kb != 0ULL) {
            unsigned a = 0xFFFFFFFFu - (unsigned)(kb & 0xFFFFFFFFu);
            if (matches[(size_t)b * A + a] < 0) a_c = (int)a;   // threshold wins
        }
        bool win = a_c >= 0;
        for (int j = 0; j < 32; ++j) {                 // last-wins dedup
            int aj = __shfl(a_c, j);
            if (j > g && a_c >= 0 && aj == a_c) win = false;
        }
        if (win) {
            const int a = a_c;
            float2 xl = *(const float2*)(lrow + a * 2);
            float x0 = xl.x, x1 = xl.y;
            float mx = fmaxf(x0, x1);
            float lse = mx + logf(expf(x0 - mx) + expf(x1 - mx));
            float xc = (lab >= 1) ? x1 : x0;
            f0 = lse - xc; f4 = 1.0f;
            float4 an = *(const float4*)(anchors + a * 4);
            const float* gb = gt_boxes + (b * G + g) * 4;
            float bx0 = gb[0], by0 = gb[1], bx1 = gb[2], by1 = gb[3];
            float gcx = (bx0 + bx1) * 0.5f, gcy = (by0 + by1) * 0.5f;
            float gw = bx1 - bx0, gh = by1 - by0;
            float off0 = ((gcx - an.x) / an.z) / VAR_C;
            float off1 = ((gcy - an.y) / an.w) / VAR_C;
            float off2 = logf(fmaxf(gw / an.z, 1e-6f)) / VAR_S;
            float off3 = logf(fmaxf(gh / an.w, 1e-6f)) / VAR_S;
            float4 bp = *(const float4*)(box_preds + ((size_t)b * A + a) * 4);
            f1 = sl1(bp.x - off0) + sl1(bp.y - off1) +
                 sl1(bp.z - off2) + sl1(bp.w - off3);
            if (lab == 1) {
                f5 = 1.0f;
                const float* gl = gt_lmk + (b * G + g) * NL * 2;
                const float* lp = lmk_preds + ((size_t)b * A + a) * (NL * 2);
                #pragma unroll
                for (int i = 0; i < NL; ++i) {
                    float tx = ((gl[2 * i] - an.x) / an.z) / VAR_C;
                    float ty = ((gl[2 * i + 1] - an.y) / an.w) / VAR_C;
                    f2 += sl1(lp[2 * i] - tx) + sl1(lp[2 * i + 1] - ty);
                }
                const float* gz = gt_gaze + (b * G + g) * 2;
                const float* gp = gaze_preds + ((size_t)b * A + a) * 2;
                f3 = sl1(gp[0] - gz[0]) + sl1(gp[1] - gz[1]);
            }
            unsigned key = krow[a];
            float closs = __uint_as_float(key ^ 0x80000000u);
            fbin = vbin(closs); fa = a;
        }
    }
    if (tid < 64) {   // wave 0 reduces (lanes 32..63 carry zeros)
        #pragma unroll
        for (int off = 16; off > 0; off >>= 1) {
            f0 += __shfl_down(f0, off); f1 += __shfl_down(f1, off);
            f2 += __shfl_down(f2, off); f3 += __shfl_down(f3, off);
            f4 += __shfl_down(f4, off); f5 += __shfl_down(f5, off);
        }
        if (tid == 0) {
            accs[0] += f0; accs[1] += f1; accs[2] += f2;
            accs[3] += f3; accs[4] += f4; accs[5] += f5;
        }
    }
    if (fbin >= 0) {
        atomicSub(&lhist[fbin], 1u);
        krow[fa] = 0u;     // now positive: excluded from neg scans
    }
    __syncthreads();

    // ---- phase 2: k + threshold bin (wave-0 shfl suffix scan) ----
    unsigned pos_t = (unsigned)accs[4];
    unsigned face_t = (unsigned)accs[5];
    unsigned num_pos = pos_t > 1u ? pos_t : 1u;
    unsigned neg_cnt = (unsigned)A - pos_t;
    unsigned k = 3u * num_pos; if (neg_cnt < k) k = neg_cnt;

    if (tid < 64) {
        unsigned c[4]; unsigned csum = 0;
        #pragma unroll
        for (int j = 0; j < 4; ++j) { c[j] = lhist[tid * 4 + j]; csum += c[j]; }
        unsigned S = csum;
        #pragma unroll
        for (int off = 1; off < 64; off <<= 1) {
            unsigned t2 = __shfl_down(S, off);
            if (tid + off < 64) S += t2;
        }
        unsigned excl = S - csum;
        if (excl < k && excl + csum >= k) {    // unique owner lane
            unsigned cum = excl;
            #pragma unroll
            for (int j = 3; j >= 0; --j) {
                unsigned h = c[j];
                if (cum + h >= k) { s_t = tid * 4 + j; s_kk = k - cum; break; }
                cum += h;
            }
        }
    }
    __syncthreads();
    const int t = s_t;
    const unsigned kk_bin = s_kk;

    // ---- phase 3: fused sum(bins>t) + ballot-aggregated compact(bin==t) ----
    float nsum_top = 0.0f;
    for (int i = tid; i < A / 4; i += ST) {
        uint4 kv = krow4[i];
        #pragma unroll
        for (int j = 0; j < 4; ++j) {
            unsigned key = (&kv.x)[j];
            bool cp = false;
            if (key != 0u) {
                float closs = __uint_as_float(key ^ 0x80000000u);
                int bin = vbin(closs);
                if (bin > t) nsum_top += closs;
                else if (bin == t) cp = true;
            }
            unsigned long long m = __ballot(cp);
            if (m != 0ULL) {
                int leader = __ffsll((long long)m) - 1;
                unsigned base = 0u;
                if (lane == leader)
                    base = atomicAdd(&s_candN, (unsigned)__popcll(m));
                base = __shfl(base, leader);
                if (cp) {
                    unsigned idx = base + (unsigned)__popcll(m & ((1ULL << lane) - 1ULL));
                    if (idx < CANDCAP) cand[idx] = key;
                }
            }
        }
    }
    __syncthreads();
    const unsigned candN = s_candN;
    const bool fast = candN <= CANDCAP;

    // ---- phase 4: exact radix select within bin t (per-wave hists) ----
    unsigned pfx = 0, kk = kk_bin;
    for (int p = 0; p < 4; ++p) {
        for (int i = tid; i < NW * 256; i += ST) ((unsigned*)whist)[i] = 0u;
        __syncthreads();
        const int shift = 24 - 8 * p;
        if (fast) {
            for (unsigned i = tid; i < candN; i += ST) {
                unsigned key = cand[i];
                if (p == 0 || (key >> (shift + 8)) == pfx)
                    atomicAdd(&whist[wv][(key >> shift) & 0xFFu], 1u);
            }
        } else {   // overflow fallback: full row with bin filter
            for (int a = tid; a < A; a += ST) {
                unsigned key = krow[a];
                if (key != 0u && vbin(__uint_as_float(key ^ 0x80000000u)) == t &&
                    (p == 0 || (key >> (shift + 8)) == pfx))
                    atomicAdd(&whist[wv][(key >> shift) & 0xFFu], 1u);
            }
        }
        __syncthreads();
        if (tid < 64) {
            unsigned c[4]; unsigned csum = 0;
            #pragma unroll
            for (int j = 0; j < 4; ++j) {
                unsigned v = 0;
                #pragma unroll
                for (int w = 0; w < NW; ++w) v += whist[w][tid * 4 + j];
                c[j] = v; csum += v;
            }
            unsigned S = csum;
            #pragma unroll
            for (int off = 1; off < 64; off <<= 1) {
                unsigned t2 = __shfl_down(S, off);
                if (tid + off < 64) S += t2;
            }
            unsigned excl = S - csum;
            if (excl < kk && excl + csum >= kk) {
                unsigned cum = excl;
                #pragma unroll
                for (int j = 3; j >= 0; --j) {
                    unsigned h = c[j];
                    if (cum + h >= kk) {
                        s_pfx = (pfx << 8) | (unsigned)(tid * 4 + j);
                        s_k2 = kk - cum;
                        break;
                    }
                    cum += h;
                }
            }
        }
        __syncthreads();
        pfx = s_pfx; kk = s_k2;
    }
    const unsigned Tkey = pfx;
    const unsigned krem = kk;
    const float Tval = __uint_as_float(Tkey ^ 0x80000000u);

    // ---- phase 5: candidate sum + wave reduce ----
    float csum2 = 0.0f;
    if (fast) {
        for (unsigned i = tid; i < candN; i += ST) {
            unsigned key = cand[i];
            if (key > Tkey) csum2 += __uint_as_float(key ^ 0x80000000u);
        }
    } else {
        for (int a = tid; a < A; a += ST) {
            unsigned key = krow[a];
            if (key != 0u) {
                float closs = __uint_as_float(key ^ 0x80000000u);
                if (vbin(closs) == t && key > Tkey) csum2 += closs;
            }
        }
    }
    float tot = nsum_top + csum2;
    #pragma unroll
    for (int off = 32; off > 0; off >>= 1) tot += __shfl_down(tot, off);
    if (lane == 0) swred[wv] = tot;
    __syncthreads();
    if (tid == 0) {
        float r = 0;
        #pragma unroll
        for (int w = 0; w < NW; ++w) r += swred[w];
        float* pr = partials + b * PF;
        pr[0] = accs[0]; pr[1] = accs[1]; pr[2] = accs[2]; pr[3] = accs[3];
        pr[4] = r + (float)krem * Tval;
        pr[5] = (float)num_pos;
        pr[6] = (float)(face_t > 1u ? face_t : 1u);
        __threadfence();
        unsigned r2 = atomicAdd(gdone, 1u);
        s_fin = (r2 == B - 1);
    }
    __syncthreads();
    if (!s_fin) return;
    __threadfence();   // acquire: all partials visible

    // ---- finalize (last block, wave 0) ----
    if (tid < 64) {
        int tt = tid;
        float ps = partials[tt * PF + 0], bs = partials[tt * PF + 1];
        float ls = partials[tt * PF + 2], gs = partials[tt * PF + 3];
        float ns = partials[tt * PF + 4], npos = partials[tt * PF + 5];
        float nf = partials[tt * PF + 6];
        #pragma unroll
        for (int o = 32; o > 0; o >>= 1) {
            ps += __shfl_down(ps, o); bs += __shfl_down(bs, o);
            ls += __shfl_down(ls, o); gs += __shfl_down(gs, o);
            ns += __shfl_down(ns, o); npos += __shfl_down(npos, o);
            nf += __shfl_down(nf, o);
        }
        if (tt == 0) {
            float tc = (ps + ns) / npos;
            float tb = bs / npos;
            float tl = ls / nf;
            float tg = gs / nf;
            out[0] = tc + 1.0f * tb + 0.5f * tl + 1.0f * tg;
            out[1] = tc; out[2] = tb; out[3] = tl; out[4] = tg;
        }
    }
}

extern "C" void kernel_launch(void* const* d_in, const int* in_sizes, int n_in,
                              void* d_out, int out_size, void* d_ws, size_t ws_size,
                              hipStream_t stream) {
    const float* cls_logits = (const float*)d_in[0];
    const float* box_preds  = (const float*)d_in[1];
    const float* lmk_preds  = (const float*)d_in[2];
    const float* gaze_preds = (const float*)d_in[3];
    const float* anchors    = (const float*)d_in[4];
    const float* gt_boxes   = (const float*)d_in[5];
    const int*   gt_labels  = (const int*)d_in[6];
    const float* gt_lmk     = (const float*)d_in[7];
    const float* gt_gaze    = (const float*)d_in[8];

    char* ws = (char*)d_ws;
    signed char* matches = (signed char*)ws;             ws += (size_t)B * A;                // 1.6 MB
    unsigned long long* gsplit = (unsigned long long*)ws; ws += (size_t)B * MSPLIT * G * 8;  // 164 KB
    unsigned* negkey = (unsigned*)ws;                    ws += (size_t)B * A * 4;            // 6.5 MB
    unsigned* bhist = (unsigned*)ws;                     ws += (size_t)B * MSPLIT * NB2 * 4; // 0.66 MB
    unsigned* candbuf = (unsigned*)ws;                   ws += (size_t)B * CANDCAP * 4;      // 2 MB
    float* psplit = (float*)ws;                          ws += (size_t)B * MSPLIT * PF * 4;  // 20 KB
    float* partials = (float*)ws;                        ws += (size_t)B * PF * 4;           // 2 KB
    unsigned* gdone = (unsigned*)ws;                     ws += 4;
    float* out = (float*)d_out;

    hipLaunchKernelGGL(fused_kernel, dim3(B, MSPLIT), dim3(256), 0, stream,
                       cls_logits, box_preds, lmk_preds, gaze_preds, anchors,
                       gt_boxes, gt_labels, gt_lmk, gt_gaze, matches, gsplit,
                       negkey, bhist, psplit, gdone);
    hipLaunchKernelGGL(select_kernel, dim3(B), dim3(ST), 0, stream,
                       cls_logits, box_preds, lmk_preds, gaze_preds, anchors,
                       gt_boxes, gt_labels, gt_lmk, gt_gaze, matches, gsplit,
                       negkey, bhist, psplit, candbuf, partials, gdone, out);
}

// Round 16
// 44.691 us; speedup vs baseline: 1.0841x; 1.0841x over previous
//
#include <hip/hip_runtime.h>
#include <stdint.h>

#define B 64
#define G 32
#define A 25600
#define NC 2
#define NL 5
#define IOU_T 0.5f
#define VAR_C 0.1f
#define VAR_S 0.2f

#define MSPLIT 20
#define MCH (A / MSPLIT)    // 1280 anchors per fused block, 5 per thread
#define NH 5
#define PF 8                // fields per psplit record

#define NB2 256             // coarse value-histogram bins
#define BSCALE2 20.0f       // bin = int(closs * 20), clamped to 255
#define CANDCAP 8192        // per-batch candidate buffer capacity
#define ST 512              // select_kernel threads
#define NW (ST / 64)        // select waves

__device__ __forceinline__ float sl1(float x) {
    float ax = fabsf(x);
    return ax < 1.0f ? 0.5f * ax * ax : ax - 0.5f;
}

__device__ __forceinline__ int vbin(float closs) {
    int bin = (int)(closs * BSCALE2);
    return bin < 0 ? 0 : (bin > NB2 - 1 ? NB2 - 1 : bin);
}

// ---------------------------------------------------------------------------
// K1 FUSED match+loss: grid (B, MSPLIT) x 256, NH=5 anchors per thread.
//  - wave-bbox early-out for the IoU loop (exact; first-max argmax fixup)
//  - anchor float4 reloaded (L2-hot) in loss phase to cap VGPRs; corner
//    values stay in registers so threshold comparisons are bit-exact
//  - epilogue: wave shfl reduces + 1 LDS hop; per-wave neg hists
//  - per-(block,gt) best keys -> gsplit overwrite; resets gdone
// ---------------------------------------------------------------------------
__global__ __launch_bounds__(256) void fused_kernel(
    const float* __restrict__ cls_logits, const float* __restrict__ box_preds,
    const float* __restrict__ lmk_preds, const float* __restrict__ gaze_preds,
    const float* __restrict__ anchors, const float* __restrict__ gt_boxes,
    const int* __restrict__ gt_labels, const float* __restrict__ gt_lmk,
    const float* __restrict__ gt_gaze, signed char* __restrict__ matches,
    unsigned long long* __restrict__ gsplit, unsigned* __restrict__ negkey,
    unsigned* __restrict__ bhist, float* __restrict__ psplit,
    unsigned* __restrict__ gdone)
{
    const int b = blockIdx.x, s = blockIdx.y, tid = threadIdx.x;
    const int lane = tid & 63, wave = tid >> 6;
    __shared__ float4 sbox[G];
    __shared__ int sgorig[G], sinv[G];
    __shared__ unsigned long long sbest[G];
    __shared__ int s_nv;
    __shared__ float sgb[G * 4], slmk[G * NL * 2], sgz[G * 2];
    __shared__ int slab[G];
    __shared__ unsigned lhist[4][NB2];
    __shared__ float wred[4][8];

    if (b == 0 && s == 0 && tid == 0) *gdone = 0u;   // reset for select

    if (tid < G) {
        sbest[tid] = 0ULL;
        int valid = gt_labels[b * G + tid] > 0;
        unsigned long long mask = __ballot(valid);
        int pfx = __popcll(mask & ((1ULL << tid) - 1ULL));
        sinv[tid] = valid ? pfx : -1;
        if (valid) {
            sbox[pfx] = *(const float4*)(gt_boxes + (b * G + tid) * 4);
            sgorig[pfx] = tid;
        }
        if (tid == 0) s_nv = (int)__popcll(mask);
    }
    for (int i = tid; i < G * 4; i += 256) sgb[i] = gt_boxes[b * G * 4 + i];
    for (int i = tid; i < G * NL * 2; i += 256) slmk[i] = gt_lmk[b * G * NL * 2 + i];
    for (int i = tid; i < G * 2; i += 256) sgz[i] = gt_gaze[b * G * 2 + i];
    if (tid < G) slab[tid] = gt_labels[b * G + tid];
    for (int i = tid; i < 4 * NB2; i += 256) ((unsigned*)lhist)[i] = 0u;
    __syncthreads();
    const int nv = s_nv;

    signed char* mrow = matches + (size_t)b * A;
    const int a0 = s * MCH;

    // ---- match phase: NH anchors per thread ----
    float ax0[NH], ay0[NH], ax1[NH], ay1[NH], aa[NH];
    #pragma unroll
    for (int h = 0; h < NH; ++h) {
        const int a = a0 + tid + 256 * h;
        float4 an = *(const float4*)(anchors + a * 4);
        ax0[h] = an.x - an.z * 0.5f;
        ay0[h] = an.y - an.w * 0.5f;
        ax1[h] = an.x + an.z * 0.5f;
        ay1[h] = an.y + an.w * 0.5f;
        aa[h] = (ax1[h] - ax0[h]) * (ay1[h] - ay0[h]);  // reference float path
    }

    // wave bbox of the NH*64 anchors this wave owns
    float wx0 = ax0[0], wy0 = ay0[0], wx1 = ax1[0], wy1 = ay1[0];
    #pragma unroll
    for (int h = 1; h < NH; ++h) {
        wx0 = fminf(wx0, ax0[h]); wy0 = fminf(wy0, ay0[h]);
        wx1 = fmaxf(wx1, ax1[h]); wy1 = fmaxf(wy1, ay1[h]);
    }
    #pragma unroll
    for (int off = 32; off > 0; off >>= 1) {
        wx0 = fminf(wx0, __shfl_down(wx0, off));
        wy0 = fminf(wy0, __shfl_down(wy0, off));
        wx1 = fmaxf(wx1, __shfl_down(wx1, off));
        wy1 = fmaxf(wy1, __shfl_down(wy1, off));
    }
    wx0 = __shfl(wx0, 0); wy0 = __shfl(wy0, 0);
    wx1 = __shfl(wx1, 0); wy1 = __shfl(wy1, 0);

    float best[NH];
    int bci[NH];
    #pragma unroll
    for (int h = 0; h < NH; ++h) { best[h] = -2.0f; bci[h] = 0; }

    for (int ci = 0; ci < nv; ++ci) {
        float4 bb = sbox[ci];                       // broadcast ds_read_b128
        if (bb.x < wx1 && bb.z > wx0 && bb.y < wy1 && bb.w > wy0) {
            float area = (bb.z - bb.x) * (bb.w - bb.y); // reference formula
            float inter[NH], iou[NH];
            bool anyh = false;
            #pragma unroll
            for (int h = 0; h < NH; ++h) {
                float iw = fmaxf(fminf(bb.z, ax1[h]) - fmaxf(bb.x, ax0[h]), 0.0f);
                float ih = fmaxf(fminf(bb.w, ay1[h]) - fmaxf(bb.y, ay0[h]), 0.0f);
                inter[h] = iw * ih;
                iou[h] = 0.0f;                      // exact: 0/den == +0.0
                anyh = anyh || (inter[h] > 0.0f);
            }
            if (__any(anyh)) {                      // wave-uniform skip
                unsigned long long km = 0ULL;
                #pragma unroll
                for (int h = 0; h < NH; ++h) {
                    iou[h] = inter[h] / (area + aa[h] - inter[h] + 1e-9f);
                    const int a = a0 + tid + 256 * h;
                    unsigned long long key =
                        ((unsigned long long)__float_as_uint(iou[h]) << 32) |
                        (unsigned)(0xFFFFFFFFu - (unsigned)a);
                    if (key > km) km = key;
                }
                #pragma unroll
                for (int off = 32; off > 0; off >>= 1) {
                    unsigned long long o = __shfl_down(km, off);
                    if (o > km) km = o;
                }
                if (lane == 0 && km > sbest[ci]) atomicMax(&sbest[ci], km);
            }
            #pragma unroll
            for (int h = 0; h < NH; ++h)
                if (iou[h] > best[h]) { best[h] = iou[h]; bci[h] = ci; }  // first-max
        } else {
            // all lanes: iou == +0 exactly; first-max argmax fixup
            #pragma unroll
            for (int h = 0; h < NH; ++h)
                if (best[h] < 0.0f) { best[h] = 0.0f; bci[h] = ci; }
        }
    }

    // ---- loss phase (match result from registers; anchor reloaded L2-hot) --
    const float* lrow = cls_logits + (size_t)b * A * NC;
    unsigned* krow = negkey + (size_t)b * A;

    float pos_sum = 0, box_sum = 0, lmk_sum = 0, gaze_sum = 0;
    float pos_cnt = 0, face_cnt = 0;

    #pragma unroll
    for (int h = 0; h < NH; ++h) {
        const int a = a0 + tid + 256 * h;
        const int v = (best[h] >= IOU_T) ? sgorig[bci[h]] : -1;
        mrow[a] = (signed char)v;
        float2 xl = *(const float2*)(lrow + a * 2);
        float x0 = xl.x, x1 = xl.y;
        float mx = fmaxf(x0, x1);
        float lse = mx + logf(expf(x0 - mx) + expf(x1 - mx));
        unsigned key = 0;
        if (v < 0) {
            float closs = lse - x0;   // label 0; closs > 0
            unsigned bits = __float_as_uint(closs);
            key = bits ^ ((bits & 0x80000000u) ? 0xFFFFFFFFu : 0x80000000u);
            atomicAdd(&lhist[wave][vbin(closs)], 1u);
        } else {
            int m = v;
            int lab = slab[m];
            float xc = (lab >= 1) ? x1 : x0;   // NC==2
            pos_sum += lse - xc;
            pos_cnt += 1.0f;
            float4 an = *(const float4*)(anchors + a * 4);   // L2-hot reload
            float dcx = an.x, dcy = an.y, dw = an.z, dh = an.w;
            float bx0 = sgb[m * 4], by0 = sgb[m * 4 + 1];
            float bx1 = sgb[m * 4 + 2], by1 = sgb[m * 4 + 3];
            float gcx = (bx0 + bx1) * 0.5f, gcy = (by0 + by1) * 0.5f;
            float gw = bx1 - bx0, gh = by1 - by0;
            float off0 = ((gcx - dcx) / dw) / VAR_C;
            float off1 = ((gcy - dcy) / dh) / VAR_C;
            float off2 = logf(fmaxf(gw / dw, 1e-6f)) / VAR_S;
            float off3 = logf(fmaxf(gh / dh, 1e-6f)) / VAR_S;
            float4 bp = *(const float4*)(box_preds + ((size_t)b * A + a) * 4);
            box_sum += sl1(bp.x - off0) + sl1(bp.y - off1) +
                       sl1(bp.z - off2) + sl1(bp.w - off3);
            if (lab == 1) {  // FACE
                face_cnt += 1.0f;
                const float* lp = lmk_preds + ((size_t)b * A + a) * (NL * 2);
                #pragma unroll
                for (int i = 0; i < NL; ++i) {
                    float tx = ((slmk[m * NL * 2 + 2 * i] - dcx) / dw) / VAR_C;
                    float ty = ((slmk[m * NL * 2 + 2 * i + 1] - dcy) / dh) / VAR_C;
                    lmk_sum += sl1(lp[2 * i] - tx) + sl1(lp[2 * i + 1] - ty);
                }
                const float* gp = gaze_preds + ((size_t)b * A + a) * 2;
                gaze_sum += sl1(gp[0] - sgz[m * 2]) + sl1(gp[1] - sgz[m * 2 + 1]);
            }
        }
        krow[a] = key;
    }

    // ---- epilogue: wave shfl reduce + 1 LDS hop (2 barriers total) ----
    #pragma unroll
    for (int off = 32; off > 0; off >>= 1) {
        pos_sum += __shfl_down(pos_sum, off);
        box_sum += __shfl_down(box_sum, off);
        lmk_sum += __shfl_down(lmk_sum, off);
        gaze_sum += __shfl_down(gaze_sum, off);
        pos_cnt += __shfl_down(pos_cnt, off);
        face_cnt += __shfl_down(face_cnt, off);
    }
    if (lane == 0) {
        wred[wave][0] = pos_sum; wred[wave][1] = box_sum;
        wred[wave][2] = lmk_sum; wred[wave][3] = gaze_sum;
        wred[wave][4] = pos_cnt; wred[wave][5] = face_cnt;
    }
    __syncthreads();   // wred + lhist + sbest all complete
    if (tid < 6) {
        psplit[(b * MSPLIT + s) * PF + tid] =
            wred[0][tid] + wred[1][tid] + wred[2][tid] + wred[3][tid];
    }
    bhist[(b * MSPLIT + s) * NB2 + tid] =
        lhist[0][tid] + lhist[1][tid] + lhist[2][tid] + lhist[3][tid];
    if (tid < G) {
        int ci = sinv[tid];
        gsplit[((size_t)b * MSPLIT + s) * G + tid] = (ci >= 0) ? sbest[ci] : 0ULL;
    }
}

// ---------------------------------------------------------------------------
// K2 select: grid B x 512.  Wave-0 shfl suffix scans, per-wave radix hists,
// ballot-aggregated compaction, forced-match fixup, last-block finalize.
// ---------------------------------------------------------------------------
__global__ __launch_bounds__(ST) void select_kernel(
    const float* __restrict__ cls_logits, const float* __restrict__ box_preds,
    const float* __restrict__ lmk_preds, const float* __restrict__ gaze_preds,
    const float* __restrict__ anchors, const float* __restrict__ gt_boxes,
    const int* __restrict__ gt_labels, const float* __restrict__ gt_lmk,
    const float* __restrict__ gt_gaze, const signed char* __restrict__ matches,
    const unsigned long long* __restrict__ gsplit,
    unsigned* __restrict__ negkey, const unsigned* __restrict__ bhist,
    const float* __restrict__ psplit, unsigned* __restrict__ candbuf,
    float* __restrict__ partials, unsigned* __restrict__ gdone,
    float* __restrict__ out)
{
    const int b = blockIdx.x, tid = threadIdx.x;
    const int lane = tid & 63, wv = tid >> 6;
    __shared__ unsigned lhist[NB2];
    __shared__ unsigned whist[NW][256];
    __shared__ float accs[8];
    __shared__ float swred[NW];
    __shared__ int s_t, s_fin;
    __shared__ unsigned s_kk, s_candN, s_pfx, s_k2;

    unsigned* krow = negkey + (size_t)b * A;
    const uint4* krow4 = (const uint4*)krow;
    const float* lrow = cls_logits + (size_t)b * A * NC;
    unsigned* cand = candbuf + (size_t)b * CANDCAP;

    // ---- phase 0: merge psplit + bhist ----
    if (tid < 6) {
        float v = 0;
        for (int s2 = 0; s2 < MSPLIT; ++s2) v += psplit[(b * MSPLIT + s2) * PF + tid];
        accs[tid] = v;
    }
    if (tid < NB2) {
        unsigned v = 0;
        const unsigned* hb = bhist + (size_t)b * MSPLIT * NB2 + tid;
        for (int s2 = 0; s2 < MSPLIT; ++s2) v += hb[s2 * NB2];
        lhist[tid] = v;
    }
    if (tid == 0) s_candN = 0;
    __syncthreads();

    // ---- phase 1: fixup (forced matches) ----
    float f0 = 0, f1 = 0, f2 = 0, f3 = 0, f4 = 0, f5 = 0;
    int fbin = -1, fa = -1;
    if (tid < 32) {
        const int g = tid;
        int lab = gt_labels[b * G + g];
        unsigned long long kb = 0ULL;
        const unsigned long long* gs = gsplit + (size_t)b * MSPLIT * G + g;
        for (int s2 = 0; s2 < MSPLIT; ++s2) {
            unsigned long long v = gs[(size_t)s2 * G];
            if (v > kb) kb = v;
        }
        int a_c = -1;
        if (lab > 0 && kb != 0ULL) {
            unsigned a = 0xFFFFFFFFu - (unsigned)(kb & 0xFFFFFFFFu);
            if (matches[(size_t)b * A + a] < 0) a_c = (int)a;   // threshold wins
        }
        bool win = a_c >= 0;
        for (int j = 0; j < 32; ++j) {                 // last-wins dedup
            int aj = __shfl(a_c, j);
            if (j > g && a_c >= 0 && aj == a_c) win = false;
        }
        if (win) {
            const int a = a_c;
            float2 xl = *(const float2*)(lrow + a * 2);
            float x0 = xl.x, x1 = xl.y;
            float mx = fmaxf(x0, x1);
            float lse = mx + logf(expf(x0 - mx) + expf(x1 - mx));
            float xc = (lab >= 1) ? x1 : x0;
            f0 = lse - xc; f4 = 1.0f;
            float4 an = *(const float4*)(anchors + a * 4);
            const float* gb = gt_boxes + (b * G + g) * 4;
            float bx0 = gb[0], by0 = gb[1], bx1 = gb[2], by1 = gb[3];
            float gcx = (bx0 + bx1) * 0.5f, gcy = (by0 + by1) * 0.5f;
            float gw = bx1 - bx0, gh = by1 - by0;
            float off0 = ((gcx - an.x) / an.z) / VAR_C;
            float off1 = ((gcy - an.y) / an.w) / VAR_C;
            float off2 = logf(fmaxf(gw / an.z, 1e-6f)) / VAR_S;
            float off3 = logf(fmaxf(gh / an.w, 1e-6f)) / VAR_S;
            float4 bp = *(const float4*)(box_preds + ((size_t)b * A + a) * 4);
            f1 = sl1(bp.x - off0) + sl1(bp.y - off1) +
                 sl1(bp.z - off2) + sl1(bp.w - off3);
            if (lab == 1) {
                f5 = 1.0f;
                const float* gl = gt_lmk + (b * G + g) * NL * 2;
                const float* lp = lmk_preds + ((size_t)b * A + a) * (NL * 2);
                #pragma unroll
                for (int i = 0; i < NL; ++i) {
                    float tx = ((gl[2 * i] - an.x) / an.z) / VAR_C;
                    float ty = ((gl[2 * i + 1] - an.y) / an.w) / VAR_C;
                    f2 += sl1(lp[2 * i] - tx) + sl1(lp[2 * i + 1] - ty);
                }
                const float* gz = gt_gaze + (b * G + g) * 2;
                const float* gp = gaze_preds + ((size_t)b * A + a) * 2;
                f3 = sl1(gp[0] - gz[0]) + sl1(gp[1] - gz[1]);
            }
            unsigned key = krow[a];
            float closs = __uint_as_float(key ^ 0x80000000u);
            fbin = vbin(closs); fa = a;
        }
    }
    if (tid < 64) {   // wave 0 reduces (lanes 32..63 carry zeros)
        #pragma unroll
        for (int off = 16; off > 0; off >>= 1) {
            f0 += __shfl_down(f0, off); f1 += __shfl_down(f1, off);
            f2 += __shfl_down(f2, off); f3 += __shfl_down(f3, off);
            f4 += __shfl_down(f4, off); f5 += __shfl_down(f5, off);
        }
        if (tid == 0) {
            accs[0] += f0; accs[1] += f1; accs[2] += f2;
            accs[3] += f3; accs[4] += f4; accs[5] += f5;
        }
    }
    if (fbin >= 0) {
        atomicSub(&lhist[fbin], 1u);
        krow[fa] = 0u;     // now positive: excluded from neg scans
    }
    __syncthreads();

    // ---- phase 2: k + threshold bin (wave-0 shfl suffix scan) ----
    unsigned pos_t = (unsigned)accs[4];
    unsigned face_t = (unsigned)accs[5];
    unsigned num_pos = pos_t > 1u ? pos_t : 1u;
    unsigned neg_cnt = (unsigned)A - pos_t;
    unsigned k = 3u * num_pos; if (neg_cnt < k) k = neg_cnt;

    if (tid < 64) {
        unsigned c[4]; unsigned csum = 0;
        #pragma unroll
        for (int j = 0; j < 4; ++j) { c[j] = lhist[tid * 4 + j]; csum += c[j]; }
        unsigned S = csum;
        #pragma unroll
        for (int off = 1; off < 64; off <<= 1) {
            unsigned t2 = __shfl_down(S, off);
            if (tid + off < 64) S += t2;
        }
        unsigned excl = S - csum;
        if (excl < k && excl + csum >= k) {    // unique owner lane
            unsigned cum = excl;
            #pragma unroll
            for (int j = 3; j >= 0; --j) {
                unsigned h = c[j];
                if (cum + h >= k) { s_t = tid * 4 + j; s_kk = k - cum; break; }
                cum += h;
            }
        }
    }
    __syncthreads();
    const int t = s_t;
    const unsigned kk_bin = s_kk;

    // ---- phase 3: fused sum(bins>t) + ballot-aggregated compact(bin==t) ----
    float nsum_top = 0.0f;
    for (int i = tid; i < A / 4; i += ST) {
        uint4 kv = krow4[i];
        #pragma unroll
        for (int j = 0; j < 4; ++j) {
            unsigned key = (&kv.x)[j];
            bool cp = false;
            if (key != 0u) {
                float closs = __uint_as_float(key ^ 0x80000000u);
                int bin = vbin(closs);
                if (bin > t) nsum_top += closs;
                else if (bin == t) cp = true;
            }
            unsigned long long m = __ballot(cp);
            if (m != 0ULL) {
                int leader = __ffsll((long long)m) - 1;
                unsigned base = 0u;
                if (lane == leader)
                    base = atomicAdd(&s_candN, (unsigned)__popcll(m));
                base = __shfl(base, leader);
                if (cp) {
                    unsigned idx = base + (unsigned)__popcll(m & ((1ULL << lane) - 1ULL));
                    if (idx < CANDCAP) cand[idx] = key;
                }
            }
        }
    }
    __syncthreads();
    const unsigned candN = s_candN;
    const bool fast = candN <= CANDCAP;

    // ---- phase 4: exact radix select within bin t (per-wave hists) ----
    unsigned pfx = 0, kk = kk_bin;
    for (int p = 0; p < 4; ++p) {
        for (int i = tid; i < NW * 256; i += ST) ((unsigned*)whist)[i] = 0u;
        __syncthreads();
        const int shift = 24 - 8 * p;
        if (fast) {
            for (unsigned i = tid; i < candN; i += ST) {
                unsigned key = cand[i];
                if (p == 0 || (key >> (shift + 8)) == pfx)
                    atomicAdd(&whist[wv][(key >> shift) & 0xFFu], 1u);
            }
        } else {   // overflow fallback: full row with bin filter
            for (int a = tid; a < A; a += ST) {
                unsigned key = krow[a];
                if (key != 0u && vbin(__uint_as_float(key ^ 0x80000000u)) == t &&
                    (p == 0 || (key >> (shift + 8)) == pfx))
                    atomicAdd(&whist[wv][(key >> shift) & 0xFFu], 1u);
            }
        }
        __syncthreads();
        if (tid < 64) {
            unsigned c[4]; unsigned csum = 0;
            #pragma unroll
            for (int j = 0; j < 4; ++j) {
                unsigned v = 0;
                #pragma unroll
                for (int w = 0; w < NW; ++w) v += whist[w][tid * 4 + j];
                c[j] = v; csum += v;
            }
            unsigned S = csum;
            #pragma unroll
            for (int off = 1; off < 64; off <<= 1) {
                unsigned t2 = __shfl_down(S, off);
                if (tid + off < 64) S += t2;
            }
            unsigned excl = S - csum;
            if (excl < kk && excl + csum >= kk) {
                unsigned cum = excl;
                #pragma unroll
                for (int j = 3; j >= 0; --j) {
                    unsigned h = c[j];
                    if (cum + h >= kk) {
                        s_pfx = (pfx << 8) | (unsigned)(tid * 4 + j);
                        s_k2 = kk - cum;
                        break;
                    }
                    cum += h;
                }
            }
        }
        __syncthreads();
        pfx = s_pfx; kk = s_k2;
    }
    const unsigned Tkey = pfx;
    const unsigned krem = kk;
    const float Tval = __uint_as_float(Tkey ^ 0x80000000u);

    // ---- phase 5: candidate sum + wave reduce ----
    float csum2 = 0.0f;
    if (fast) {
        for (unsigned i = tid; i < candN; i += ST) {
            unsigned key = cand[i];
            if (key > Tkey) csum2 += __uint_as_float(key ^ 0x80000000u);
        }
    } else {
        for (int a = tid; a < A; a += ST) {
            unsigned key = krow[a];
            if (key != 0u) {
                float closs = __uint_as_float(key ^ 0x80000000u);
                if (vbin(closs) == t && key > Tkey) csum2 += closs;
            }
        }
    }
    float tot = nsum_top + csum2;
    #pragma unroll
    for (int off = 32; off > 0; off >>= 1) tot += __shfl_down(tot, off);
    if (lane == 0) swred[wv] = tot;
    __syncthreads();
    if (tid == 0) {
        float r = 0;
        #pragma unroll
        for (int w = 0; w < NW; ++w) r += swred[w];
        float* pr = partials + b * PF;
        pr[0] = accs[0]; pr[1] = accs[1]; pr[2] = accs[2]; pr[3] = accs[3];
        pr[4] = r + (float)krem * Tval;
        pr[5] = (float)num_pos;
        pr[6] = (float)(face_t > 1u ? face_t : 1u);
        __threadfence();
        unsigned r2 = atomicAdd(gdone, 1u);
        s_fin = (r2 == B - 1);
    }
    __syncthreads();
    if (!s_fin) return;
    __threadfence();   // acquire: all partials visible

    // ---- finalize (last block, wave 0) ----
    if (tid < 64) {
        int tt = tid;
        float ps = partials[tt * PF + 0], bs = partials[tt * PF + 1];
        float ls = partials[tt * PF + 2], gs = partials[tt * PF + 3];
        float ns = partials[tt * PF + 4], npos = partials[tt * PF + 5];
        float nf = partials[tt * PF + 6];
        #pragma unroll
        for (int o = 32; o > 0; o >>= 1) {
            ps += __shfl_down(ps, o); bs += __shfl_down(bs, o);
            ls += __shfl_down(ls, o); gs += __shfl_down(gs, o);
            ns += __shfl_down(ns, o); npos += __shfl_down(npos, o);
            nf += __shfl_down(nf, o);
        }
        if (tt == 0) {
            float tc = (ps + ns) / npos;
            float tb = bs / npos;
            float tl = ls / nf;
            float tg = gs / nf;
            out[0] = tc + 1.0f * tb + 0.5f * tl + 1.0f * tg;
            out[1] = tc; out[2] = tb; out[3] = tl; out[4] = tg;
        }
    }
}

extern "C" void kernel_launch(void* const* d_in, const int* in_sizes, int n_in,
                              void* d_out, int out_size, void* d_ws, size_t ws_size,
                              hipStream_t stream) {
    const float* cls_logits = (const float*)d_in[0];
    const float* box_preds  = (const float*)d_in[1];
    const float* lmk_preds  = (const float*)d_in[2];
    const float* gaze_preds = (const float*)d_in[3];
    const float* anchors    = (const float*)d_in[4];
    const float* gt_boxes   = (const float*)d_in[5];
    const int*   gt_labels  = (const int*)d_in[6];
    const float* gt_lmk     = (const float*)d_in[7];
    const float* gt_gaze    = (const float*)d_in[8];

    char* ws = (char*)d_ws;
    signed char* matches = (signed char*)ws;             ws += (size_t)B * A;                // 1.6 MB
    unsigned long long* gsplit = (unsigned long long*)ws; ws += (size_t)B * MSPLIT * G * 8;  // 328 KB
    unsigned* negkey = (unsigned*)ws;                    ws += (size_t)B * A * 4;            // 6.5 MB
    unsigned* bhist = (unsigned*)ws;                     ws += (size_t)B * MSPLIT * NB2 * 4; // 1.3 MB
    unsigned* candbuf = (unsigned*)ws;                   ws += (size_t)B * CANDCAP * 4;      // 2 MB
    float* psplit = (float*)ws;                          ws += (size_t)B * MSPLIT * PF * 4;  // 41 KB
    float* partials = (float*)ws;                        ws += (size_t)B * PF * 4;           // 2 KB
    unsigned* gdone = (unsigned*)ws;                     ws += 4;
    float* out = (float*)d_out;

    hipLaunchKernelGGL(fused_kernel, dim3(B, MSPLIT), dim3(256), 0, stream,
                       cls_logits, box_preds, lmk_preds, gaze_preds, anchors,
                       gt_boxes, gt_labels, gt_lmk, gt_gaze, matches, gsplit,
                       negkey, bhist, psplit, gdone);
    hipLaunchKernelGGL(select_kernel, dim3(B), dim3(ST), 0, stream,
                       cls_logits, box_preds, lmk_preds, gaze_preds, anchors,
                       gt_boxes, gt_labels, gt_lmk, gt_gaze, matches, gsplit,
                       negkey, bhist, psplit, candbuf, partials, gdone, out);
}